// Round 1
// baseline (14489.374 us; speedup 1.0000x reference)
//
#include <hip/hip_runtime.h>
#include <hip/hip_bf16.h>

#define NB 256
#define NS 512
#define ND 128
#define NH 256

#define C2LE 2.8853900817779268f   // 2*log2(e)
#define LOG2E 1.4426950408889634f

static __device__ __forceinline__ float bfu(unsigned short u) {
  return __uint_as_float(((unsigned)u) << 16);
}
static __device__ __forceinline__ float blo(unsigned q) { return __uint_as_float(q << 16); }
static __device__ __forceinline__ float bhi(unsigned q) { return __uint_as_float(q & 0xFFFF0000u); }

static __device__ __forceinline__ float dot4(ushort4 w, float4 h, float acc) {
  acc = fmaf(bfu(w.x), h.x, acc);
  acc = fmaf(bfu(w.y), h.y, acc);
  acc = fmaf(bfu(w.z), h.z, acc);
  acc = fmaf(bfu(w.w), h.w, acc);
  return acc;
}
// tanh-term: inputs pre-scaled by 2*log2(e). tanh(x) = 1 - 2/(1+e^{2x})
static __device__ __forceinline__ float tterm(float phs, float pxs, float vw, float acc) {
  float uu = __builtin_amdgcn_exp2f(phs + pxs);
  float r  = __builtin_amdgcn_rcpf(1.0f + uu);
  float th = fmaf(-2.0f, r, 1.0f);
  return fmaf(vw, th, acc);
}
static __device__ __forceinline__ float sigm(float xv) {
  float uu = __builtin_amdgcn_exp2f(-xv * LOG2E);
  return __builtin_amdgcn_rcpf(1.0f + uu);
}
static __device__ __forceinline__ float tanhe(float xv) {
  float uu = __builtin_amdgcn_exp2f(xv * C2LE);
  return fmaf(-2.0f, __builtin_amdgcn_rcpf(1.0f + uu), 1.0f);
}

// ---------------- prep kernels (pack weights to bf16, transposed layouts) ----

// Whp[j4][o][k] = bf16(W_ue[o][4*j4+k]),  j4<128, o<512, k<4
__global__ void k_pack_wh(const float* __restrict__ wue, __hip_bfloat16* __restrict__ whp) {
  for (int idx = blockIdx.x * blockDim.x + threadIdx.x; idx < 128 * 512 * 4;
       idx += gridDim.x * blockDim.x) {
    int k = idx & 3, o = (idx >> 2) & 511, j4 = idx >> 11;
    whp[idx] = __float2bfloat16(wue[o * 1024 + 4 * j4 + k]);
  }
}
// Wihp[d4][g][k] = bf16(W_ih[g][4*d4+k]), d4<32, g<1024
__global__ void k_pack_wih(const float* __restrict__ wih, __hip_bfloat16* __restrict__ wp) {
  for (int idx = blockIdx.x * blockDim.x + threadIdx.x; idx < 32 * 1024 * 4;
       idx += gridDim.x * blockDim.x) {
    int k = idx & 3, g = (idx >> 2) & 1023, d4 = idx >> 12;
    wp[idx] = __float2bfloat16(wih[g * 128 + 4 * d4 + k]);
  }
}
// Whhp[j4][g][k] = bf16(W_hh[g][4*j4+k]), j4<64, g<1024
__global__ void k_pack_whh(const float* __restrict__ whh, __hip_bfloat16* __restrict__ wp) {
  for (int idx = blockIdx.x * blockDim.x + threadIdx.x; idx < 64 * 1024 * 4;
       idx += gridDim.x * blockDim.x) {
    int k = idx & 3, g = (idx >> 2) & 1023, j4 = idx >> 12;
    wp[idx] = __float2bfloat16(whh[g * 256 + 4 * j4 + k]);
  }
}
// WxT[s][o] = W_ue[o][512+s]  (f32)
__global__ void k_wxt(const float* __restrict__ wue, float* __restrict__ wxt) {
  for (int idx = blockIdx.x * blockDim.x + threadIdx.x; idx < 512 * 512;
       idx += gridDim.x * blockDim.x) {
    int o = idx & 511, s = idx >> 9;
    wxt[idx] = wue[o * 1024 + 512 + s];
  }
}
__global__ void k_bsum(const float* __restrict__ bih, const float* __restrict__ bhh,
                       float* __restrict__ bs) {
  int idx = blockIdx.x * blockDim.x + threadIdx.x;
  if (idx < 1024) bs[idx] = bih[idx] + bhh[idx];
}

// ---------------- proj_x precompute ----------------
// px[b][d][o] = bf16( C2LE * sum_s x[b,s,d] * WxT[s][o] ),  stored pre-scaled
__global__ __launch_bounds__(512) void k_projx(const float* __restrict__ x,
                                               const float* __restrict__ wxt,
                                               __hip_bfloat16* __restrict__ px) {
  __shared__ alignas(16) float xsT[32][512];  // [dd][s]
  const int b = blockIdx.x;
  const int tid = threadIdx.x;
  for (int dt = 0; dt < 4; ++dt) {
    __syncthreads();
    // load x[b, s=tid, dt*32 .. +32) into xsT[dd][tid]
    const float4* xr = (const float4*)(x + ((size_t)b << 16) + (size_t)tid * 128 + dt * 32);
#pragma unroll
    for (int q = 0; q < 8; ++q) {
      float4 vx = xr[q];
      xsT[q * 4 + 0][tid] = vx.x;
      xsT[q * 4 + 1][tid] = vx.y;
      xsT[q * 4 + 2][tid] = vx.z;
      xsT[q * 4 + 3][tid] = vx.w;
    }
    __syncthreads();
    const int o = tid;
    float acc[32];
#pragma unroll
    for (int dd = 0; dd < 32; ++dd) acc[dd] = 0.f;
    for (int s4 = 0; s4 < 128; ++s4) {
      float w0 = wxt[(s4 * 4 + 0) * 512 + o];
      float w1 = wxt[(s4 * 4 + 1) * 512 + o];
      float w2 = wxt[(s4 * 4 + 2) * 512 + o];
      float w3 = wxt[(s4 * 4 + 3) * 512 + o];
#pragma unroll
      for (int dd = 0; dd < 32; ++dd) {
        float4 xv = *(const float4*)&xsT[dd][s4 * 4];
        acc[dd] = fmaf(w0, xv.x, fmaf(w1, xv.y, fmaf(w2, xv.z, fmaf(w3, xv.w, acc[dd]))));
      }
    }
    for (int dd = 0; dd < 32; ++dd) {
      px[((size_t)b * 128 + dt * 32 + dd) * 512 + o] = __float2bfloat16(acc[dd] * C2LE);
    }
  }
}

// ---------------- main persistent scan kernel: one block per batch element ----
__global__ __launch_bounds__(1024) void k_main(
    const float* __restrict__ x, const float* __restrict__ ve,
    const __hip_bfloat16* __restrict__ px, const ushort4* __restrict__ whp,
    const ushort4* __restrict__ wihp, const ushort4* __restrict__ whhp,
    const float* __restrict__ bsum, float* __restrict__ out) {
  __shared__ alignas(16) float hs[512];     // h[0:256], c[256:512]
  __shared__ alignas(16) float ph[512];     // proj_h pre-scaled by C2LE
  __shared__ alignas(16) float phtmp[1024];
  __shared__ alignas(16) float vv[512];
  __shared__ alignas(16) float epart[1024];
  __shared__ alignas(16) float esh[128];
  __shared__ alignas(16) float u_l[128];    // x_t * exp(E)  (unnormalized)
  __shared__ alignas(16) float garr[1024];
  __shared__ float zinv_sh;

  const int b = blockIdx.x;
  const int tid = threadIdx.x;

  if (tid < 512) {
    hs[tid] = 0.f;
    vv[tid] = ve[tid];
  }
  __syncthreads();

  for (int t = 0; t < NS; ++t) {
    // ---- Phase 1: proj_h[o] = C2LE * sum_j hs[j]*W_h[o,j] (split j over 2 halves)
    {
      const int o = tid & 511, half = tid >> 9;
      const ushort4* wp = whp + (size_t)(half * 64) * 512 + o;
      const int jbase = half * 256;
      float acc = 0.f;
#pragma unroll 4
      for (int j4 = 0; j4 < 64; ++j4) {
        ushort4 w = wp[(size_t)j4 * 512];
        float4 hv = *(const float4*)&hs[jbase + j4 * 4];
        acc = dot4(w, hv, acc);
      }
      phtmp[tid] = acc;
    }
    __syncthreads();
    if (tid < 512) ph[tid] = (phtmp[tid] + phtmp[tid + 512]) * C2LE;
    __syncthreads();

    // ---- Phase 2: E[d] partials over s (128 d x 8 s-chunks of 64)
    {
      const int d = tid >> 3, sc = tid & 7;
      const uint4* pr = (const uint4*)(px + (((size_t)b * 128 + d) * 512 + sc * 64));
      float acc = 0.f;
#pragma unroll 2
      for (int i8 = 0; i8 < 8; ++i8) {
        uint4 q = pr[i8];
        int s0 = sc * 64 + i8 * 8;
        float4 pa = *(const float4*)&ph[s0];
        float4 pb = *(const float4*)&ph[s0 + 4];
        float4 va = *(const float4*)&vv[s0];
        float4 vb = *(const float4*)&vv[s0 + 4];
        acc = tterm(pa.x, blo(q.x), va.x, acc);
        acc = tterm(pa.y, bhi(q.x), va.y, acc);
        acc = tterm(pa.z, blo(q.y), va.z, acc);
        acc = tterm(pa.w, bhi(q.y), va.w, acc);
        acc = tterm(pb.x, blo(q.z), vb.x, acc);
        acc = tterm(pb.y, bhi(q.z), vb.y, acc);
        acc = tterm(pb.z, blo(q.w), vb.z, acc);
        acc = tterm(pb.w, bhi(q.w), vb.w, acc);
      }
      epart[tid] = acc;
    }
    __syncthreads();
    if (tid < 128) {
      const float* e8 = &epart[tid * 8];
      float E = ((e8[0] + e8[1]) + (e8[2] + e8[3])) + ((e8[4] + e8[5]) + (e8[6] + e8[7]));
      float e = __builtin_amdgcn_exp2f(E * LOG2E);  // exp(E), no max needed (|E| bounded)
      float xt = x[((size_t)b << 16) + (size_t)t * 128 + tid];
      u_l[tid] = xt * e;
      esh[tid] = e;
    }
    __syncthreads();
    if (tid < 64) {
      float z = esh[tid] + esh[tid + 64];
#pragma unroll
      for (int m = 32; m; m >>= 1) z += __shfl_xor(z, m);
      if (tid == 0) zinv_sh = __builtin_amdgcn_rcpf(z);
    }
    __syncthreads();

    // ---- Phase 3: gates[g] = (sum_d u[d]*W_ih[g,d]) * zinv + bsum[g] + sum_j h[j]*W_hh[g,j]
    {
      const int g = tid;
      float accx = 0.f;
      const ushort4* wi = wihp + g;
#pragma unroll 4
      for (int d4 = 0; d4 < 32; ++d4) {
        ushort4 w = wi[(size_t)d4 * 1024];
        float4 uv = *(const float4*)&u_l[d4 * 4];
        accx = dot4(w, uv, accx);
      }
      float acc = fmaf(accx, zinv_sh, bsum[g]);
      const ushort4* wh = whhp + g;
#pragma unroll 4
      for (int j4 = 0; j4 < 64; ++j4) {
        ushort4 w = wh[(size_t)j4 * 1024];
        float4 hv = *(const float4*)&hs[j4 * 4];  // h part only (j<256)
        acc = dot4(w, hv, acc);
      }
      garr[g] = acc;
    }
    __syncthreads();

    // ---- Phase 4: LSTM pointwise update + output write
    if (tid < 256) {
      const int j = tid;
      float gi = garr[j], gf = garr[256 + j], gg = garr[512 + j], go = garr[768 + j];
      float i_ = sigm(gi);
      float f_ = sigm(gf);
      float g_ = tanhe(gg);
      float o_ = sigm(go);
      float c_new = fmaf(f_, hs[256 + j], i_ * g_);
      float h_new = o_ * tanhe(c_new);
      hs[j] = h_new;
      hs[256 + j] = c_new;
      out[((size_t)t * 256 + b) * 256 + j] = h_new;
    }
    __syncthreads();
  }
}

// ---------------- host ----------------
extern "C" void kernel_launch(void* const* d_in, const int* in_sizes, int n_in,
                              void* d_out, int out_size, void* d_ws, size_t ws_size,
                              hipStream_t stream) {
  const float* x    = (const float*)d_in[0];
  const float* wue  = (const float*)d_in[1];
  const float* ve   = (const float*)d_in[2];
  const float* wih  = (const float*)d_in[3];
  const float* whh  = (const float*)d_in[4];
  const float* bih  = (const float*)d_in[5];
  const float* bhh  = (const float*)d_in[6];
  float* out = (float*)d_out;

  char* ws = (char*)d_ws;
  // ws layout (all 16B-aligned)
  __hip_bfloat16* px   = (__hip_bfloat16*)(ws);                    // 33,554,432 B
  __hip_bfloat16* whp  = (__hip_bfloat16*)(ws + 33554432);         //    524,288 B
  __hip_bfloat16* wihp = (__hip_bfloat16*)(ws + 34078720);         //    262,144 B
  __hip_bfloat16* whhp = (__hip_bfloat16*)(ws + 34340864);         //    524,288 B
  float* bsum          = (float*)(ws + 34865152);                  //      4,096 B
  float* wxt           = (float*)(ws + 34869248);                  //  1,048,576 B
  // total: 35,917,824 B

  k_pack_wh<<<256, 256, 0, stream>>>(wue, whp);
  k_pack_wih<<<128, 256, 0, stream>>>(wih, wihp);
  k_pack_whh<<<256, 256, 0, stream>>>(whh, whhp);
  k_wxt<<<256, 256, 0, stream>>>(wue, wxt);
  k_bsum<<<4, 256, 0, stream>>>(bih, bhh, bsum);
  k_projx<<<256, 512, 0, stream>>>(x, wxt, px);
  k_main<<<256, 1024, 0, stream>>>(x, ve, px, (const ushort4*)whp, (const ushort4*)wihp,
                                   (const ushort4*)whhp, bsum, out);
}

// Round 3
// 10219.690 us; speedup vs baseline: 1.4178x; 1.4178x over previous
//
#include <hip/hip_runtime.h>
#include <hip/hip_bf16.h>

#define C2LE 2.8853900817779268f   // 2*log2(e)
#define LOG2E 1.4426950408889634f

static __device__ __forceinline__ float blo(unsigned q) { return __uint_as_float(q << 16); }
static __device__ __forceinline__ float bhi(unsigned q) { return __uint_as_float(q & 0xFFFF0000u); }

static __device__ __forceinline__ float dot8(uint4 q, float4 a, float4 b, float acc) {
  acc = fmaf(blo(q.x), a.x, acc); acc = fmaf(bhi(q.x), a.y, acc);
  acc = fmaf(blo(q.y), a.z, acc); acc = fmaf(bhi(q.y), a.w, acc);
  acc = fmaf(blo(q.z), b.x, acc); acc = fmaf(bhi(q.z), b.y, acc);
  acc = fmaf(blo(q.w), b.z, acc); acc = fmaf(bhi(q.w), b.w, acc);
  return acc;
}
// r = 1/(1+2^arg)  (arg pre-scaled by 2*log2e);  tanh = 1 - 2r
static __device__ __forceinline__ float rterm(float arg) {
  return __builtin_amdgcn_rcpf(1.0f + __builtin_amdgcn_exp2f(arg));
}
static __device__ __forceinline__ float sigm(float x) {
  return __builtin_amdgcn_rcpf(1.0f + __builtin_amdgcn_exp2f(-x * LOG2E));
}
static __device__ __forceinline__ float tanhe(float x) {
  return fmaf(-2.0f, __builtin_amdgcn_rcpf(1.0f + __builtin_amdgcn_exp2f(x * C2LE)), 1.0f);
}

// ---------------- pack kernels ----------------
// whp[cc][o][k8] bf16, cc<64, o<512, k8<8 ; j = (cc>>5)*256 + (cc&31)*8 + k8
__global__ void k_pack_wh(const float* __restrict__ wue, __hip_bfloat16* __restrict__ wp) {
  for (int idx = blockIdx.x * blockDim.x + threadIdx.x; idx < 64 * 512 * 8;
       idx += gridDim.x * blockDim.x) {
    int k8 = idx & 7, o = (idx >> 3) & 511, cc = idx >> 12;
    int j = (cc >> 5) * 256 + (cc & 31) * 8 + k8;
    wp[idx] = __float2bfloat16(wue[o * 1024 + j]);
  }
}
// wihp[d8][g][k8], d8<16, g<1024
__global__ void k_pack_wih(const float* __restrict__ wih, __hip_bfloat16* __restrict__ wp) {
  for (int idx = blockIdx.x * blockDim.x + threadIdx.x; idx < 16 * 1024 * 8;
       idx += gridDim.x * blockDim.x) {
    int k8 = idx & 7, g = (idx >> 3) & 1023, d8 = idx >> 13;
    wp[idx] = __float2bfloat16(wih[g * 128 + d8 * 8 + k8]);
  }
}
// whhp[j8][g][k8], j8<32, g<1024
__global__ void k_pack_whh(const float* __restrict__ whh, __hip_bfloat16* __restrict__ wp) {
  for (int idx = blockIdx.x * blockDim.x + threadIdx.x; idx < 32 * 1024 * 8;
       idx += gridDim.x * blockDim.x) {
    int k8 = idx & 7, g = (idx >> 3) & 1023, j8 = idx >> 13;
    wp[idx] = __float2bfloat16(whh[g * 256 + j8 * 8 + k8]);
  }
}
// WxT[s][o] = W_ue[o][512+s]
__global__ void k_wxt(const float* __restrict__ wue, float* __restrict__ wxt) {
  for (int idx = blockIdx.x * blockDim.x + threadIdx.x; idx < 512 * 512;
       idx += gridDim.x * blockDim.x) {
    int o = idx & 511, s = idx >> 9;
    wxt[idx] = wue[o * 1024 + 512 + s];
  }
}

// ---------------- proj_x precompute: px[b][d][o] = bf16(C2LE * sum_s x[b,s,d]*WxT[s][o]) ----
__global__ __launch_bounds__(512) void k_projx(const float* __restrict__ x,
                                               const float* __restrict__ wxt,
                                               __hip_bfloat16* __restrict__ px) {
  __shared__ alignas(16) float xsT[32][512];
  const int b = blockIdx.x;
  const int tid = threadIdx.x;
  for (int dt = 0; dt < 4; ++dt) {
    __syncthreads();
    const float4* xr = (const float4*)(x + ((size_t)b << 16) + (size_t)tid * 128 + dt * 32);
#pragma unroll
    for (int q = 0; q < 8; ++q) {
      float4 vx = xr[q];
      xsT[q * 4 + 0][tid] = vx.x;
      xsT[q * 4 + 1][tid] = vx.y;
      xsT[q * 4 + 2][tid] = vx.z;
      xsT[q * 4 + 3][tid] = vx.w;
    }
    __syncthreads();
    const int o = tid;
    float acc[32];
#pragma unroll
    for (int dd = 0; dd < 32; ++dd) acc[dd] = 0.f;
    for (int s4 = 0; s4 < 128; ++s4) {
      float w0 = wxt[(s4 * 4 + 0) * 512 + o];
      float w1 = wxt[(s4 * 4 + 1) * 512 + o];
      float w2 = wxt[(s4 * 4 + 2) * 512 + o];
      float w3 = wxt[(s4 * 4 + 3) * 512 + o];
#pragma unroll
      for (int dd = 0; dd < 32; ++dd) {
        float4 xv = *(const float4*)&xsT[dd][s4 * 4];
        acc[dd] = fmaf(w0, xv.x, fmaf(w1, xv.y, fmaf(w2, xv.z, fmaf(w3, xv.w, acc[dd]))));
      }
    }
    for (int dd = 0; dd < 32; ++dd) {
      px[((size_t)b * 128 + dt * 32 + dd) * 512 + o] = __float2bfloat16(acc[dd] * C2LE);
    }
  }
}

// ---------------- main persistent scan kernel: one block per batch element ----
__global__ __launch_bounds__(1024) void k_main(
    const float* __restrict__ x, const float* __restrict__ ve,
    const __hip_bfloat16* __restrict__ px, const uint4* __restrict__ whp,
    const uint4* __restrict__ wihp, const uint4* __restrict__ whhp,
    const float* __restrict__ bih, const float* __restrict__ bhh,
    float* __restrict__ out) {
  __shared__ alignas(16) uint4  px_lds[8192];   // 128 KB: [d][s] bf16, 64 uint4 per row
  __shared__ alignas(16) float  ph_t[512];      // [e][c] transposed proj_h, pre-scaled C2LE
  __shared__ alignas(16) float  vv_t[512];      // [e][c] transposed v
  __shared__ alignas(16) float  esh[128];
  __shared__ alignas(16) float  u_l[128];       // x_t * exp(E) (unnormalized)
  __shared__ alignas(16) float  garr[1024];
  __shared__ alignas(16) float  bs_l[1024];
  __shared__ alignas(16) float  hs[512];        // h[0:256], c[256:512]
  __shared__ float vsum_sh;

  const int b = blockIdx.x;
  const int tid = threadIdx.x;

  // ---- prologue: stage px into LDS, transpose v, biases, zero state
  {
    const uint4* src = (const uint4*)(px + ((size_t)b << 16));
#pragma unroll
    for (int i = 0; i < 8; ++i) px_lds[tid + i * 1024] = src[tid + i * 1024];
  }
  if (tid < 512) {
    vv_t[(tid & 7) * 64 + (tid >> 3)] = ve[tid];
    hs[tid] = 0.f;
  }
  bs_l[tid] = bih[tid] + bhh[tid];
  if (tid < 64) {
    float s = 0.f;
#pragma unroll
    for (int k = 0; k < 8; ++k) s += ve[tid + k * 64];
#pragma unroll
    for (int m = 1; m < 64; m <<= 1) s += __shfl_xor(s, m);
    if (tid == 0) vsum_sh = s;
  }
  __syncthreads();
  const float vsum = vsum_sh;

  for (int t = 0; t < 512; ++t) {
    // ---- Phase 1: proj_h[o] = C2LE * sum_j hs[j]*W_h[o,j]; pair-split over j-halves
    {
      const int o = tid >> 1, half = tid & 1;
      const uint4* wp = whp + (size_t)(half * 32) * 512 + o;
      const float4* hv = (const float4*)&hs[half * 256];
      float acc = 0.f;
#pragma unroll 8
      for (int j8 = 0; j8 < 32; ++j8) {
        uint4 q = wp[(size_t)j8 * 512];
        acc = dot8(q, hv[j8 * 2], hv[j8 * 2 + 1], acc);
      }
      acc += __shfl_xor(acc, 1);
      if (half == 0) ph_t[(o & 7) * 64 + (o >> 3)] = acc * C2LE;
    }
    __syncthreads();

    // ---- Phase 2: E-partials; thread = (chunk c of 8 o's, group of 8 d's)
    {
      const int c = tid & 63, dgrp = tid >> 6;
      float phr[8], vvr[8];
#pragma unroll
      for (int e = 0; e < 8; ++e) {
        phr[e] = ph_t[e * 64 + c];
        vvr[e] = vv_t[e * 64 + c];
      }
      float acc[8];
#pragma unroll
      for (int dd = 0; dd < 8; ++dd) acc[dd] = 0.f;
#pragma unroll
      for (int dd = 0; dd < 8; ++dd) {
        uint4 q = px_lds[(dgrp * 8 + dd) * 64 + c];  // row stride = 64 uint4 (FIXED)
        float a = acc[dd];
        a = fmaf(vvr[0], rterm(phr[0] + blo(q.x)), a);
        a = fmaf(vvr[1], rterm(phr[1] + bhi(q.x)), a);
        a = fmaf(vvr[2], rterm(phr[2] + blo(q.y)), a);
        a = fmaf(vvr[3], rterm(phr[3] + bhi(q.y)), a);
        a = fmaf(vvr[4], rterm(phr[4] + blo(q.z)), a);
        a = fmaf(vvr[5], rterm(phr[5] + bhi(q.z)), a);
        a = fmaf(vvr[6], rterm(phr[6] + blo(q.w)), a);
        a = fmaf(vvr[7], rterm(phr[7] + bhi(q.w)), a);
        acc[dd] = a;
      }
#pragma unroll
      for (int dd = 0; dd < 8; ++dd) {
        float a = acc[dd];
#pragma unroll
        for (int m = 1; m < 64; m <<= 1) a += __shfl_xor(a, m);
        acc[dd] = a;
      }
      if (c < 8) {
        float Ea = acc[0];
#pragma unroll
        for (int k = 1; k < 8; ++k) Ea = (c == k) ? acc[k] : Ea;
        const int d = dgrp * 8 + c;
        float E = vsum - 2.0f * Ea;               // sum_o v*tanh
        float e = __builtin_amdgcn_exp2f(E * LOG2E);
        float xt = x[((size_t)b << 16) + (size_t)t * 128 + d];
        esh[d] = e;
        u_l[d] = xt * e;
      }
    }
    __syncthreads();

    // ---- Phase 3: gates[g] = (W_ih·u)*zinv + bsum + W_hh·h
    {
      const int g = tid;
      float accx = 0.f;
      const uint4* wi = wihp + g;
      const float4* uv = (const float4*)u_l;
#pragma unroll 8
      for (int d8 = 0; d8 < 16; ++d8) {
        uint4 q = wi[(size_t)d8 * 1024];
        accx = dot8(q, uv[d8 * 2], uv[d8 * 2 + 1], accx);
      }
      float acch = 0.f;
      const uint4* wh = whhp + g;
      const float4* hv = (const float4*)hs;
#pragma unroll 8
      for (int j8 = 0; j8 < 32; ++j8) {
        uint4 q = wh[(size_t)j8 * 1024];
        acch = dot8(q, hv[j8 * 2], hv[j8 * 2 + 1], acch);
      }
      // redundant per-wave z-reduction (no extra barrier)
      const int lane = tid & 63;
      float z = esh[lane] + esh[64 + lane];
#pragma unroll
      for (int m = 1; m < 64; m <<= 1) z += __shfl_xor(z, m);
      float zinv = __builtin_amdgcn_rcpf(z);
      garr[g] = fmaf(accx, zinv, bs_l[g] + acch);
    }
    __syncthreads();

    // ---- Phase 4: LSTM pointwise + output
    if (tid < 256) {
      const int j = tid;
      float gi = garr[j], gf = garr[256 + j], gg = garr[512 + j], go = garr[768 + j];
      float i_ = sigm(gi);
      float f_ = sigm(gf);
      float g_ = tanhe(gg);
      float o_ = sigm(go);
      float c_new = fmaf(f_, hs[256 + j], i_ * g_);
      float h_new = o_ * tanhe(c_new);
      hs[j] = h_new;
      hs[256 + j] = c_new;
      __builtin_nontemporal_store(h_new, &out[((size_t)t * 256 + b) * 256 + j]);
    }
    __syncthreads();
  }
}

// ---------------- host ----------------
extern "C" void kernel_launch(void* const* d_in, const int* in_sizes, int n_in,
                              void* d_out, int out_size, void* d_ws, size_t ws_size,
                              hipStream_t stream) {
  const float* x   = (const float*)d_in[0];
  const float* wue = (const float*)d_in[1];
  const float* ve  = (const float*)d_in[2];
  const float* wih = (const float*)d_in[3];
  const float* whh = (const float*)d_in[4];
  const float* bih = (const float*)d_in[5];
  const float* bhh = (const float*)d_in[6];
  float* out = (float*)d_out;

  char* ws = (char*)d_ws;
  __hip_bfloat16* px   = (__hip_bfloat16*)(ws);             // 33,554,432 B
  __hip_bfloat16* whp  = (__hip_bfloat16*)(ws + 33554432);  //    524,288 B
  __hip_bfloat16* wihp = (__hip_bfloat16*)(ws + 34078720);  //    262,144 B
  __hip_bfloat16* whhp = (__hip_bfloat16*)(ws + 34340864);  //    524,288 B
  float* wxt           = (float*)(ws + 34865152);           //  1,048,576 B
  // total: 35,913,728 B

  k_pack_wh<<<256, 256, 0, stream>>>(wue, whp);
  k_pack_wih<<<128, 256, 0, stream>>>(wih, wihp);
  k_pack_whh<<<256, 256, 0, stream>>>(whh, whhp);
  k_wxt<<<256, 256, 0, stream>>>(wue, wxt);
  k_projx<<<256, 512, 0, stream>>>(x, wxt, px);
  k_main<<<256, 1024, 0, stream>>>(x, ve, px, (const uint4*)whp, (const uint4*)wihp,
                                   (const uint4*)whhp, bih, bhh, out);
}